// Round 1
// baseline (2244.046 us; speedup 1.0000x reference)
//
#include <hip/hip_runtime.h>
#include <hip/hip_bf16.h>
#include <cstdint>
#include <cstddef>

// Problem constants
#define MM 2048     // B*T
#define HH 1024     // H
#define EE 50000    // episodic memory size
#define EPAD 50048  // E padded to multiple of 64
#define KC 2048     // 2*H (concat dim)

typedef __attribute__((ext_vector_type(8))) short short8;   // 8 bf16 (4 VGPRs) MFMA A/B frag
typedef __attribute__((ext_vector_type(4))) float floatx4;  // MFMA C/D frag
typedef unsigned short ushort_t;

// ---------- helpers ----------
__device__ __forceinline__ ushort_t f2b(float f) {
    union { float f; uint32_t u; } c; c.f = f;
    uint32_t u = c.u;
    u += 0x7fffu + ((u >> 16) & 1u);   // round-to-nearest-even
    return (ushort_t)(u >> 16);
}
__device__ __forceinline__ float b2f(ushort_t h) {
    union { uint32_t u; float f; } c; c.u = ((uint32_t)h) << 16;
    return c.f;
}

// ---------- K0: convert x (fp32) -> bf16 ----------
__global__ __launch_bounds__(256) void k0_convert_x(const float* __restrict__ x,
                                                    ushort_t* __restrict__ xb) {
    int i = (blockIdx.x * 256 + threadIdx.x) * 8;  // grid covers MM*HH exactly
    float4 v0 = *(const float4*)(x + i);
    float4 v1 = *(const float4*)(x + i + 4);
    union { uint4 v; ushort_t u[8]; } pk;
    pk.u[0] = f2b(v0.x); pk.u[1] = f2b(v0.y); pk.u[2] = f2b(v0.z); pk.u[3] = f2b(v0.w);
    pk.u[4] = f2b(v1.x); pk.u[5] = f2b(v1.y); pk.u[6] = f2b(v1.z); pk.u[7] = f2b(v1.w);
    *(uint4*)(xb + i) = pk.v;
}

// ---------- K1: P = exp(x @ W_epi^T + b_epi), bf16, padded cols -> 0 ----------
// grid (32 mblk, 782 eblk), block 256. Tile 64x64, BK=32.
__global__ __launch_bounds__(256) void k1_logits_exp(const ushort_t* __restrict__ xb,
                                                     const float* __restrict__ W,
                                                     const float* __restrict__ bias,
                                                     ushort_t* __restrict__ P) {
    __shared__ ushort_t sA[64][40];
    __shared__ ushort_t sB[64][40];
    const int m0 = blockIdx.x * 64;
    const int e0 = blockIdx.y * 64;
    const int t = threadIdx.x;
    const int wv = t >> 6, l = t & 63, ml = l & 15, quad = l >> 4;
    const int wm = (wv & 1) * 32, we = (wv >> 1) * 32;
    const int sr = t >> 2;          // staging row 0..63
    const int sc = (t & 3) * 8;     // staging col 0,8,16,24
    const int erow = e0 + sr;

    floatx4 acc[2][2];
#pragma unroll
    for (int i = 0; i < 2; i++)
#pragma unroll
        for (int j = 0; j < 2; j++) acc[i][j] = (floatx4)(0.0f);

    for (int k0 = 0; k0 < HH; k0 += 32) {
        uint4 av = *(const uint4*)(xb + (size_t)(m0 + sr) * HH + k0 + sc);
        union { uint4 v; ushort_t u[8]; } bw;
        if (erow < EE) {
            const float* wp = W + (size_t)erow * HH + k0 + sc;
            float4 w0 = *(const float4*)(wp);
            float4 w1 = *(const float4*)(wp + 4);
            bw.u[0] = f2b(w0.x); bw.u[1] = f2b(w0.y); bw.u[2] = f2b(w0.z); bw.u[3] = f2b(w0.w);
            bw.u[4] = f2b(w1.x); bw.u[5] = f2b(w1.y); bw.u[6] = f2b(w1.z); bw.u[7] = f2b(w1.w);
        } else {
            bw.v = make_uint4(0u, 0u, 0u, 0u);
        }
        __syncthreads();
        *(uint4*)&sA[sr][sc] = av;
        *(uint4*)&sB[sr][sc] = bw.v;
        __syncthreads();

        short8 a0 = *(const short8*)&sA[wm + ml][quad * 8];
        short8 a1 = *(const short8*)&sA[wm + 16 + ml][quad * 8];
        short8 b0 = *(const short8*)&sB[we + ml][quad * 8];
        short8 b1 = *(const short8*)&sB[we + 16 + ml][quad * 8];
        acc[0][0] = __builtin_amdgcn_mfma_f32_16x16x32_bf16(a0, b0, acc[0][0], 0, 0, 0);
        acc[0][1] = __builtin_amdgcn_mfma_f32_16x16x32_bf16(a0, b1, acc[0][1], 0, 0, 0);
        acc[1][0] = __builtin_amdgcn_mfma_f32_16x16x32_bf16(a1, b0, acc[1][0], 0, 0, 0);
        acc[1][1] = __builtin_amdgcn_mfma_f32_16x16x32_bf16(a1, b1, acc[1][1], 0, 0, 0);
    }

#pragma unroll
    for (int ie = 0; ie < 2; ie++) {
        int eg = e0 + we + ie * 16 + ml;
        bool valid = (eg < EE);
        float bb = valid ? bias[eg] : 0.0f;
#pragma unroll
        for (int im = 0; im < 2; im++) {
            int mg = m0 + wm + im * 16 + quad * 4;
#pragma unroll
            for (int r = 0; r < 4; r++) {
                float p = valid ? __expf(acc[im][ie][r] + bb) : 0.0f;
                P[(size_t)(mg + r) * EPAD + eg] = f2b(p);
            }
        }
    }
}

// ---------- K_den: den[m] = sum_e P[m][e] ----------
__global__ __launch_bounds__(256) void k_den(const ushort_t* __restrict__ P,
                                             float* __restrict__ den) {
    const int m = blockIdx.x;
    const ushort_t* row = P + (size_t)m * EPAD;
    float s = 0.0f;
    for (int i = threadIdx.x * 8; i < EPAD; i += 2048) {
        union { uint4 v; ushort_t u[8]; } pk;
        pk.v = *(const uint4*)(row + i);
#pragma unroll
        for (int j = 0; j < 8; j++) s += b2f(pk.u[j]);
    }
#pragma unroll
    for (int off = 32; off > 0; off >>= 1) s += __shfl_down(s, off);
    __shared__ float part[4];
    if ((threadIdx.x & 63) == 0) part[threadIdx.x >> 6] = s;
    __syncthreads();
    if (threadIdx.x == 0) den[m] = part[0] + part[1] + part[2] + part[3];
}

// ---------- K2: num += P @ epi_mem (split-K atomics) ----------
// grid (32 mblk, 4 hblk, 4 ksplit), block 256. Block tile 64(m) x 256(h); wave tile 64x64.
__global__ __launch_bounds__(256) void k2_pv(const ushort_t* __restrict__ P,
                                             const float* __restrict__ mem,
                                             float* __restrict__ num) {
    __shared__ ushort_t sP[64][40];
    __shared__ ushort_t sB[32][260];   // [k(e)][h], padded
    const int m0 = blockIdx.x * 64;
    const int h0 = blockIdx.y * 256;
    const int e0 = blockIdx.z * (EPAD / 4);
    const int t = threadIdx.x;
    const int wv = t >> 6, l = t & 63, ml = l & 15, quad = l >> 4;
    const int hw = wv * 64;           // wave's h offset within block tile
    const int pr = t >> 2, pc = (t & 3) * 8;
    const int be = t >> 3;            // 0..31  (e row)
    const int bh = (t & 7) * 32;      // 0..224 (h col base)

    floatx4 acc[4][4];
#pragma unroll
    for (int i = 0; i < 4; i++)
#pragma unroll
        for (int j = 0; j < 4; j++) acc[i][j] = (floatx4)(0.0f);

    for (int it = 0; it < (EPAD / 4) / 32; ++it) {
        const int ek = e0 + it * 32;
        uint4 pv = *(const uint4*)(P + (size_t)(m0 + pr) * EPAD + ek + pc);
        uint2 pm[8];
        const int eg = ek + be;
        if (eg < EE) {
            const float* mp = mem + (size_t)eg * HH + h0 + bh;
#pragma unroll
            for (int j = 0; j < 8; j++) {
                float4 v = *(const float4*)(mp + 4 * j);
                union { ushort_t u[4]; uint2 w; } pk;
                pk.u[0] = f2b(v.x); pk.u[1] = f2b(v.y); pk.u[2] = f2b(v.z); pk.u[3] = f2b(v.w);
                pm[j] = pk.w;
            }
        } else {
#pragma unroll
            for (int j = 0; j < 8; j++) pm[j] = make_uint2(0u, 0u);
        }
        __syncthreads();
        *(uint4*)&sP[pr][pc] = pv;
#pragma unroll
        for (int j = 0; j < 8; j++) *(uint2*)&sB[be][bh + 4 * j] = pm[j];
        __syncthreads();

        short8 afr[4];
#pragma unroll
        for (int im = 0; im < 4; im++) afr[im] = *(const short8*)&sP[im * 16 + ml][quad * 8];
#pragma unroll
        for (int ih = 0; ih < 4; ih++) {
            const int hc = hw + ih * 16 + ml;
            union { ushort_t u[8]; short8 v; } bb;
#pragma unroll
            for (int j = 0; j < 8; j++) bb.u[j] = sB[quad * 8 + j][hc];
#pragma unroll
            for (int im = 0; im < 4; im++)
                acc[im][ih] = __builtin_amdgcn_mfma_f32_16x16x32_bf16(afr[im], bb.v, acc[im][ih], 0, 0, 0);
        }
    }

#pragma unroll
    for (int im = 0; im < 4; im++) {
        const int mg = m0 + im * 16 + quad * 4;
#pragma unroll
        for (int ih = 0; ih < 4; ih++) {
            const int hg = h0 + hw + ih * 16 + ml;
#pragma unroll
            for (int r = 0; r < 4; r++)
                atomicAdd(&num[(size_t)(mg + r) * HH + hg], acc[im][ih][r]);
        }
    }
}

// ---------- K3: out = concat(num/den, x) @ W_cons^T + b_cons ----------
// grid (32 mblk, 16 hblk), block 256. Tile 64x64, K=2048.
__global__ __launch_bounds__(256) void k3_final(const float* __restrict__ num,
                                                const float* __restrict__ den,
                                                const ushort_t* __restrict__ xb,
                                                const float* __restrict__ Wc,
                                                const float* __restrict__ bc,
                                                float* __restrict__ out) {
    __shared__ ushort_t sA[64][40];
    __shared__ ushort_t sB[64][40];
    const int m0 = blockIdx.x * 64;
    const int h0 = blockIdx.y * 64;
    const int t = threadIdx.x;
    const int wv = t >> 6, l = t & 63, ml = l & 15, quad = l >> 4;
    const int wm = (wv & 1) * 32, we = (wv >> 1) * 32;
    const int sr = t >> 2;
    const int sc = (t & 3) * 8;
    const float rden = 1.0f / den[m0 + sr];

    floatx4 acc[2][2];
#pragma unroll
    for (int i = 0; i < 2; i++)
#pragma unroll
        for (int j = 0; j < 2; j++) acc[i][j] = (floatx4)(0.0f);

    for (int k0 = 0; k0 < KC; k0 += 32) {
        union { uint4 v; ushort_t u[8]; } aw;
        if (k0 < HH) {
            const float* np = num + (size_t)(m0 + sr) * HH + k0 + sc;
            float4 v0 = *(const float4*)(np);
            float4 v1 = *(const float4*)(np + 4);
            aw.u[0] = f2b(v0.x * rden); aw.u[1] = f2b(v0.y * rden);
            aw.u[2] = f2b(v0.z * rden); aw.u[3] = f2b(v0.w * rden);
            aw.u[4] = f2b(v1.x * rden); aw.u[5] = f2b(v1.y * rden);
            aw.u[6] = f2b(v1.z * rden); aw.u[7] = f2b(v1.w * rden);
        } else {
            aw.v = *(const uint4*)(xb + (size_t)(m0 + sr) * HH + (k0 - HH) + sc);
        }
        union { uint4 v; ushort_t u[8]; } bw;
        {
            const float* wp = Wc + (size_t)(h0 + sr) * KC + k0 + sc;
            float4 w0 = *(const float4*)(wp);
            float4 w1 = *(const float4*)(wp + 4);
            bw.u[0] = f2b(w0.x); bw.u[1] = f2b(w0.y); bw.u[2] = f2b(w0.z); bw.u[3] = f2b(w0.w);
            bw.u[4] = f2b(w1.x); bw.u[5] = f2b(w1.y); bw.u[6] = f2b(w1.z); bw.u[7] = f2b(w1.w);
        }
        __syncthreads();
        *(uint4*)&sA[sr][sc] = aw.v;
        *(uint4*)&sB[sr][sc] = bw.v;
        __syncthreads();

        short8 a0 = *(const short8*)&sA[wm + ml][quad * 8];
        short8 a1 = *(const short8*)&sA[wm + 16 + ml][quad * 8];
        short8 b0 = *(const short8*)&sB[we + ml][quad * 8];
        short8 b1 = *(const short8*)&sB[we + 16 + ml][quad * 8];
        acc[0][0] = __builtin_amdgcn_mfma_f32_16x16x32_bf16(a0, b0, acc[0][0], 0, 0, 0);
        acc[0][1] = __builtin_amdgcn_mfma_f32_16x16x32_bf16(a0, b1, acc[0][1], 0, 0, 0);
        acc[1][0] = __builtin_amdgcn_mfma_f32_16x16x32_bf16(a1, b0, acc[1][0], 0, 0, 0);
        acc[1][1] = __builtin_amdgcn_mfma_f32_16x16x32_bf16(a1, b1, acc[1][1], 0, 0, 0);
    }

#pragma unroll
    for (int ie = 0; ie < 2; ie++) {
        const int hg = h0 + we + ie * 16 + ml;
        const float bb = bc[hg];
#pragma unroll
        for (int im = 0; im < 2; im++) {
            const int mg = m0 + wm + im * 16 + quad * 4;
#pragma unroll
            for (int r = 0; r < 4; r++)
                out[(size_t)(mg + r) * HH + hg] = acc[im][ie][r] + bb;
        }
    }
}

// ---------- sentinel: workspace too small (diagnosable via absmax ~12345) ----------
__global__ void ws_too_small_sentinel(float* __restrict__ out, int n) {
    int i = blockIdx.x * 256 + threadIdx.x;
    if (i < n) out[i] = -12345.0f;
}

extern "C" void kernel_launch(void* const* d_in, const int* in_sizes, int n_in,
                              void* d_out, int out_size, void* d_ws, size_t ws_size,
                              hipStream_t stream) {
    const float* x      = (const float*)d_in[0];
    const float* W_epi  = (const float*)d_in[1];
    const float* b_epi  = (const float*)d_in[2];
    const float* epimem = (const float*)d_in[3];
    // d_in[4..6] = W_sem, b_sem, sem_mem : dead code in the reference, skipped
    const float* W_cons = (const float*)d_in[7];
    const float* b_cons = (const float*)d_in[8];
    float* out = (float*)d_out;

    const size_t XB_OFF  = 0;
    const size_t XB_B    = (size_t)MM * HH * 2;          //   4 MiB
    const size_t P_OFF   = XB_OFF + XB_B;
    const size_t P_B     = (size_t)MM * EPAD * 2;        // ~195 MiB
    const size_t NUM_OFF = P_OFF + P_B;
    const size_t NUM_B   = (size_t)MM * HH * 4;          //   8 MiB
    const size_t DEN_OFF = NUM_OFF + NUM_B;
    const size_t DEN_B   = (size_t)MM * 4;
    const size_t NEED    = DEN_OFF + DEN_B;

    if (ws_size < NEED) {
        ws_too_small_sentinel<<<(out_size + 255) / 256, 256, 0, stream>>>(out, out_size);
        return;
    }

    ushort_t* xb  = (ushort_t*)((char*)d_ws + XB_OFF);
    ushort_t* P   = (ushort_t*)((char*)d_ws + P_OFF);
    float*    num = (float*)((char*)d_ws + NUM_OFF);
    float*    den = (float*)((char*)d_ws + DEN_OFF);

    k0_convert_x<<<(MM * HH) / (256 * 8), 256, 0, stream>>>(x, xb);
    k1_logits_exp<<<dim3(MM / 64, EPAD / 64), 256, 0, stream>>>(xb, W_epi, b_epi, P);
    k_den<<<MM, 256, 0, stream>>>(P, den);
    hipMemsetAsync(num, 0, NUM_B, stream);
    k2_pv<<<dim3(MM / 64, HH / 256, 4), 256, 0, stream>>>(P, epimem, num);
    k3_final<<<dim3(MM / 64, HH / 64), 256, 0, stream>>>(num, den, xb, W_cons, b_cons, out);
}